// Round 10
// baseline (140.926 us; speedup 1.0000x reference)
//
#include <hip/hip_runtime.h>

#define BB 2
#define NN 16384
#define KK 4096
#define CC 128
#define SS 32

typedef float vfloat4 __attribute__((ext_vector_type(4)));

// ---------------------------------------------------------------------------
// Kernel A: transpose features [B][C][N] -> [B][N][C] (512B contiguous rows),
// PLUS fused xyzw prep. UNCHANGED (absmax 0.0 verified rounds 2/4/6/7/8).
// ---------------------------------------------------------------------------
__global__ __launch_bounds__(256) void transpose_prep_kernel(
    const float* __restrict__ feat, const float* __restrict__ xyz,
    float* __restrict__ feat_t, float* __restrict__ xyzw)
{
    __shared__ float tile[64][133];
    const int b  = blockIdx.x >> 8;          // NN/64 = 256 tiles per batch
    const int n0 = (blockIdx.x & 255) * 64;
    const int t  = threadIdx.x;

    if (t < 64) {
        const int i = b * NN + n0 + t;
        const float* p = xyz + (size_t)i * 3;
        const float x = p[0], y = p[1], z = p[2];
        const float pp = __fadd_rn(__fadd_rn(__fmul_rn(x, x), __fmul_rn(y, y)),
                                   __fmul_rn(z, z));
        vfloat4 v = {x, y, z, pp};
        *(vfloat4*)(xyzw + (size_t)i * 4) = v;
    }

    const int ln = t & 63;
    const int cr = t >> 6;                   // 0..3
#pragma unroll
    for (int p = 0; p < 32; ++p) {
        const int c = p * 4 + cr;
        tile[ln][c] = feat[((size_t)b * CC + c) * NN + n0 + ln];
    }
    __syncthreads();

    const int cl = t & 31;
    const int ns = t >> 5;                   // 0..7
#pragma unroll
    for (int p = 0; p < 8; ++p) {
        const int n = ns + 8 * p;
        float* dst = feat_t + ((size_t)(b * NN + n0 + n)) * CC;
#pragma unroll
        for (int j = 0; j < 4; ++j)
            dst[cl + 32 * j] = tile[n][cl + 32 * j];
    }
}

// ---------------------------------------------------------------------------
// Kernel B: ball query. UNCHANGED from round 7/8.
// ---------------------------------------------------------------------------
__global__ __launch_bounds__(256) void ball_query_kernel(
    const float* __restrict__ xyzw,      // [B][N][4]
    const float* __restrict__ new_xyz,   // [B][K][3]
    int* __restrict__ idx_buf)           // [B*K][S]
{
    const int wave = threadIdx.x >> 6;
    const int lane = threadIdx.x & 63;
    const int qi   = blockIdx.x * 4 + wave;
    const int b    = qi >> 12;                   // K = 4096
    const int k    = qi & (KK - 1);

    const float R2 = (float)(0.4 * 0.4);

    const float* q = new_xyz + (size_t)(b * KK + k) * 3;
    const float qx = q[0], qy = q[1], qz = q[2];
    const float qq = __fadd_rn(__fadd_rn(__fmul_rn(qx, qx), __fmul_rn(qy, qy)),
                               __fmul_rn(qz, qz));

    const vfloat4* xw = (const vfloat4*)xyzw + (size_t)b * NN;
    int* out = idx_buf + (size_t)qi * SS;

    int cnt = 0;
    int first = -1;

    auto process = [&](int base, vfloat4 v) {
        const float dot = __fadd_rn(__fadd_rn(__fmul_rn(qx, v.x), __fmul_rn(qy, v.y)),
                                    __fmul_rn(qz, v.z));
        const float d2 = __fsub_rn(__fadd_rn(qq, v.w), __fmul_rn(2.0f, dot));
        const bool inball = d2 < R2;
        const unsigned long long mask = __ballot(inball);
        if (mask) {
            if (first < 0) first = base + (int)__builtin_ctzll(mask);
            if (inball) {
                const int pos = cnt + __popcll(mask & ((1ull << lane) - 1ull));
                if (pos < SS) out[pos] = base + lane;
            }
            cnt += __popcll(mask);
        }
    };

    vfloat4 v0 = xw[lane];
    vfloat4 v1 = xw[64 + lane];
    vfloat4 v2 = xw[128 + lane];
    vfloat4 v3 = xw[192 + lane];

    for (int base = 0; base < NN; base += 256) {
        const int nb = (base + 256 < NN) ? base + 256 : 0;   // clamp; unused vals
        vfloat4 u0 = xw[nb + lane];
        vfloat4 u1 = xw[nb + 64 + lane];
        vfloat4 u2 = xw[nb + 128 + lane];
        vfloat4 u3 = xw[nb + 192 + lane];

        process(base, v0);
        process(base + 64, v1);
        process(base + 128, v2);
        process(base + 192, v3);
        if (cnt >= SS) break;

        v0 = u0; v1 = u1; v2 = u2; v3 = u3;
    }

    const int fill = (first < 0) ? 0 : first;
    if (lane < SS && lane >= cnt) out[lane] = fill;
}

// ---------------------------------------------------------------------------
// Kernel C: grouping — MEASUREMENT PROBE round. blockIdx.y = replica 0..7.
// All replicas run the gather DMA + swizzled LDS-read phase; only replica 0
// stores. Replicas 1..7 sink values via asm volatile (keeps work live, rule
// #17). Purpose: (a) lift group_kernel above the 80us fill dispatches so its
// counters appear in top-5; (b) solve dur = 8*G + W for the phase split.
// REVERT the replication next round.
// ---------------------------------------------------------------------------
__global__ __launch_bounds__(256) void group_kernel(
    const float* __restrict__ xyzw,      // [B][N][4]
    const float* __restrict__ new_xyz,   // [B][K][3]
    const float* __restrict__ feat_t,    // [B][N][C]
    const int*   __restrict__ idx_buf,   // [B*K][S]
    float* __restrict__ out)             // [B][3][K][S] ++ [B][C][K][S]
{
    __shared__ float tile[SS * CC];      // 32 rows x 512B, linear, chunk-swizzled
    __shared__ float txyz[3][SS];

    const int t      = threadIdx.x;
    const int l      = t & 63;
    const int w      = t >> 6;           // wave 0..3
    const int bk     = blockIdx.x;
    const bool writer = (blockIdx.y == 0);
    const int b      = bk >> 12;
    const int k      = bk & (KK - 1);
    const int half   = l >> 5;           // 0..1
    const int cl     = l & 31;           // chunk slot within row

    // Gather: wave w, iter p stages sample rows r=8w+2p and r+1 (1KB DMA).
#pragma unroll
    for (int p = 0; p < 4; ++p) {
        const int r = 8 * w + 2 * p;                 // wave-uniform row base
        const int s = r + half;
        const int n = idx_buf[bk * SS + s];
        const int chunk = cl ^ ((s >> 2) & 7);
        const float* src = feat_t + ((size_t)(b * NN + n)) * CC + 4 * chunk;
        __builtin_amdgcn_global_load_lds(
            (const __attribute__((address_space(1))) void*)src,
            (__attribute__((address_space(3))) void*)(tile + r * CC),
            16, 0, 0);
    }

    if (writer && t < SS) {
        const int n = idx_buf[bk * SS + t];
        const float* q = new_xyz + (size_t)bk * 3;
        const vfloat4 wv = *((const vfloat4*)xyzw + (size_t)b * NN + n);
        txyz[0][t] = (wv.x - q[0]) / 0.4f;
        txyz[1][t] = (wv.y - q[1]) / 0.4f;
        txyz[2][t] = (wv.z - q[2]) / 0.4f;
    }

    __syncthreads();   // drains vmcnt(0): all DMAs (+ txyz for writer) visible

    float* out_xyz  = out;
    float* out_feat = out + (size_t)BB * 3 * KK * SS;

    const int sq = t & 7;
    const int c0 = t >> 3;               // 0..31
#pragma unroll
    for (int p = 0; p < 4; ++p) {
        const int c  = c0 + 32 * p;
        const int co = (((c >> 2) ^ sq) << 2) + (c & 3);   // un-swizzled col
        vfloat4 v;
        v.x = tile[(4 * sq + 0) * CC + co];
        v.y = tile[(4 * sq + 1) * CC + co];
        v.z = tile[(4 * sq + 2) * CC + co];
        v.w = tile[(4 * sq + 3) * CC + co];
        if (writer) {
            __builtin_nontemporal_store(
                v, (vfloat4*)(out_feat + (((size_t)(b * CC + c) * KK + k) * SS + 4 * sq)));
        } else {
            asm volatile("" :: "v"(v.x), "v"(v.y), "v"(v.z), "v"(v.w));
        }
    }

    if (writer && t < 24) {
        const int d   = t >> 3;
        const int sq2 = t & 7;
        const vfloat4 v = *(vfloat4*)&txyz[d][4 * sq2];
        __builtin_nontemporal_store(
            v, (vfloat4*)(out_xyz + (((size_t)(b * 3 + d) * KK + k) * SS + 4 * sq2)));
    }
}

extern "C" void kernel_launch(void* const* d_in, const int* in_sizes, int n_in,
                              void* d_out, int out_size, void* d_ws, size_t ws_size,
                              hipStream_t stream) {
    const float* xyz     = (const float*)d_in[0];   // [2][16384][3]
    const float* new_xyz = (const float*)d_in[1];   // [2][4096][3]
    const float* feat    = (const float*)d_in[2];   // [2][128][16384]
    float* out = (float*)d_out;

    // Workspace layout (17.5 MB total):
    int*   idx_buf = (int*)d_ws;                                  // 1 MB
    float* xyzw    = (float*)((char*)d_ws + (1 << 20));           // 512 KB
    float* feat_t  = (float*)((char*)d_ws + (1 << 20) + (512 << 10)); // 16 MB

    transpose_prep_kernel<<<dim3(BB * (NN / 64)), dim3(256), 0, stream>>>(
        feat, xyz, feat_t, xyzw);

    ball_query_kernel<<<dim3(BB * KK / 4), dim3(256), 0, stream>>>(
        xyzw, new_xyz, idx_buf);

    // PROBE: grid.y = 8 replicas (7 gather-only + 1 writer). Revert next round.
    group_kernel<<<dim3(BB * KK, 8), dim3(256), 0, stream>>>(
        xyzw, new_xyz, feat_t, idx_buf, out);
}

// Round 11
// 101.594 us; speedup vs baseline: 1.3872x; 1.3872x over previous
//
#include <hip/hip_runtime.h>

#define BB 2
#define NN 16384
#define KK 4096
#define CC 128
#define SS 32

typedef float vfloat4 __attribute__((ext_vector_type(4)));

// ---------------------------------------------------------------------------
// Kernel A: transpose features [B][C][N] -> [B][N][C] (512B contiguous rows),
// PLUS fused xyzw prep. UNCHANGED (absmax 0.0 verified rounds 2/4/6/7/8/10).
// ---------------------------------------------------------------------------
__global__ __launch_bounds__(256) void transpose_prep_kernel(
    const float* __restrict__ feat, const float* __restrict__ xyz,
    float* __restrict__ feat_t, float* __restrict__ xyzw)
{
    __shared__ float tile[64][133];
    const int b  = blockIdx.x >> 8;          // NN/64 = 256 tiles per batch
    const int n0 = (blockIdx.x & 255) * 64;
    const int t  = threadIdx.x;

    if (t < 64) {
        const int i = b * NN + n0 + t;
        const float* p = xyz + (size_t)i * 3;
        const float x = p[0], y = p[1], z = p[2];
        const float pp = __fadd_rn(__fadd_rn(__fmul_rn(x, x), __fmul_rn(y, y)),
                                   __fmul_rn(z, z));
        vfloat4 v = {x, y, z, pp};
        *(vfloat4*)(xyzw + (size_t)i * 4) = v;
    }

    const int ln = t & 63;
    const int cr = t >> 6;                   // 0..3
#pragma unroll
    for (int p = 0; p < 32; ++p) {
        const int c = p * 4 + cr;
        tile[ln][c] = feat[((size_t)b * CC + c) * NN + n0 + ln];
    }
    __syncthreads();

    const int cl = t & 31;
    const int ns = t >> 5;                   // 0..7
#pragma unroll
    for (int p = 0; p < 8; ++p) {
        const int n = ns + 8 * p;
        float* dst = feat_t + ((size_t)(b * NN + n0 + n)) * CC;
#pragma unroll
        for (int j = 0; j < 4; ++j)
            dst[cl + 32 * j] = tile[n][cl + 32 * j];
    }
}

// ---------------------------------------------------------------------------
// Kernel B: ball query v3 — L2-BW fix. Round-10 probe showed ball ~50us with
// per-wave streaming at ~21 TB/s from L2 (demand > ceiling). Now the block's
// 4 waves SHARE each 256-pt chunk via a double-buffered LDS tile (L2 traffic
// /4), with block-uniform early exit via __syncthreads_and. Per-chunk test
// restructured for ILP: 4 independent ballots, then one guarded append.
// Float exprs EXACTLY match reference (no fma, left-assoc) -> absmax 0.0.
// ---------------------------------------------------------------------------
__global__ __launch_bounds__(256) void ball_query_kernel(
    const float* __restrict__ xyzw,      // [B][N][4]
    const float* __restrict__ new_xyz,   // [B][K][3]
    int* __restrict__ idx_buf)           // [B*K][S]
{
    __shared__ vfloat4 pts[256];         // 4 KB chunk tile

    const int t    = threadIdx.x;
    const int wave = t >> 6;
    const int lane = t & 63;
    const int qi   = blockIdx.x * 4 + wave;
    const int b    = qi >> 12;                   // K = 4096
    const int k    = qi & (KK - 1);

    const float R2 = (float)(0.4 * 0.4);

    const float* q = new_xyz + (size_t)(b * KK + k) * 3;
    const float qx = q[0], qy = q[1], qz = q[2];
    const float qq = __fadd_rn(__fadd_rn(__fmul_rn(qx, qx), __fmul_rn(qy, qy)),
                               __fmul_rn(qz, qz));

    const vfloat4* xw = (const vfloat4*)xyzw + (size_t)b * NN;
    int* out = idx_buf + (size_t)qi * SS;

    int cnt = 0;

    // Prologue: stage chunk 0.
    pts[t] = xw[t];
    __syncthreads();

    for (int base = 0; base < NN; base += 256) {
        // Issue next chunk's load early (latency hides under compute).
        const int nb = (base + 256 < NN) ? base + 256 : 0;   // clamp; values unused
        const vfloat4 nxt = xw[nb + t];

        if (cnt < SS) {
            // 4 independent ballots (ILP), then one guarded append block.
            vfloat4 v0 = pts[lane];
            vfloat4 v1 = pts[64 + lane];
            vfloat4 v2 = pts[128 + lane];
            vfloat4 v3 = pts[192 + lane];

            auto d2test = [&](vfloat4 v) -> bool {
                const float dot = __fadd_rn(
                    __fadd_rn(__fmul_rn(qx, v.x), __fmul_rn(qy, v.y)),
                    __fmul_rn(qz, v.z));
                const float d2 = __fsub_rn(__fadd_rn(qq, v.w), __fmul_rn(2.0f, dot));
                return d2 < R2;
            };

            const bool i0 = d2test(v0);
            const bool i1 = d2test(v1);
            const bool i2 = d2test(v2);
            const bool i3 = d2test(v3);
            const unsigned long long m0 = __ballot(i0);
            const unsigned long long m1 = __ballot(i1);
            const unsigned long long m2 = __ballot(i2);
            const unsigned long long m3 = __ballot(i3);

            const int c0 = cnt;
            const int p0 = __popcll(m0), p1 = __popcll(m1);
            const int p2 = __popcll(m2), p3 = __popcll(m3);
            cnt = c0 + p0 + p1 + p2 + p3;

            if ((m0 | m1 | m2 | m3) != 0ull && c0 < SS) {
                const unsigned long long lt = (1ull << lane) - 1ull;
                int bs = c0;
                if (i0) { const int pos = bs + __popcll(m0 & lt);
                          if (pos < SS) out[pos] = base + lane; }
                bs += p0;
                if (i1) { const int pos = bs + __popcll(m1 & lt);
                          if (pos < SS) out[pos] = base + 64 + lane; }
                bs += p1;
                if (i2) { const int pos = bs + __popcll(m2 & lt);
                          if (pos < SS) out[pos] = base + 128 + lane; }
                bs += p2;
                if (i3) { const int pos = bs + __popcll(m3 & lt);
                          if (pos < SS) out[pos] = base + 192 + lane; }
            }
        }

        // Block-uniform exit; also guarantees all LDS reads are done.
        if (__syncthreads_and(cnt >= SS)) break;

        pts[t] = nxt;          // stage next chunk
        __syncthreads();       // writes visible before next compute
    }

    // Tail fill: slots >= cnt get the first in-ball index (out[0]), or 0.
    const int fill = (cnt > 0) ? out[0] : 0;
    if (lane < SS && lane >= cnt) out[lane] = fill;
}

// ---------------------------------------------------------------------------
// Kernel C: grouping. REVERTED to round-8 single-copy form (probe removed).
// gload_lds DMA gather (G~7us) + chunk-XOR-swizzled linear LDS (0 bank
// conflicts, validated round 10) + nontemporal [C][S] writes (W~24us).
// ---------------------------------------------------------------------------
__global__ __launch_bounds__(256) void group_kernel(
    const float* __restrict__ xyzw,      // [B][N][4]
    const float* __restrict__ new_xyz,   // [B][K][3]
    const float* __restrict__ feat_t,    // [B][N][C]
    const int*   __restrict__ idx_buf,   // [B*K][S]
    float* __restrict__ out)             // [B][3][K][S] ++ [B][C][K][S]
{
    __shared__ float tile[SS * CC];      // 32 rows x 512B, linear, chunk-swizzled
    __shared__ float txyz[3][SS];

    const int t    = threadIdx.x;
    const int l    = t & 63;
    const int w    = t >> 6;             // wave 0..3
    const int bk   = blockIdx.x;
    const int b    = bk >> 12;
    const int k    = bk & (KK - 1);
    const int half = l >> 5;             // 0..1
    const int cl   = l & 31;             // chunk slot within row

#pragma unroll
    for (int p = 0; p < 4; ++p) {
        const int r = 8 * w + 2 * p;                 // wave-uniform row base
        const int s = r + half;
        const int n = idx_buf[bk * SS + s];
        const int chunk = cl ^ ((s >> 2) & 7);
        const float* src = feat_t + ((size_t)(b * NN + n)) * CC + 4 * chunk;
        __builtin_amdgcn_global_load_lds(
            (const __attribute__((address_space(1))) void*)src,
            (__attribute__((address_space(3))) void*)(tile + r * CC),
            16, 0, 0);
    }

    if (t < SS) {
        const int n = idx_buf[bk * SS + t];
        const float* q = new_xyz + (size_t)bk * 3;
        const vfloat4 wv = *((const vfloat4*)xyzw + (size_t)b * NN + n);
        txyz[0][t] = (wv.x - q[0]) / 0.4f;
        txyz[1][t] = (wv.y - q[1]) / 0.4f;
        txyz[2][t] = (wv.z - q[2]) / 0.4f;
    }

    __syncthreads();   // drains vmcnt(0): all DMAs + txyz visible

    float* out_xyz  = out;
    float* out_feat = out + (size_t)BB * 3 * KK * SS;

    const int sq = t & 7;
    const int c0 = t >> 3;               // 0..31
#pragma unroll
    for (int p = 0; p < 4; ++p) {
        const int c  = c0 + 32 * p;
        const int co = (((c >> 2) ^ sq) << 2) + (c & 3);   // un-swizzled col
        vfloat4 v;
        v.x = tile[(4 * sq + 0) * CC + co];
        v.y = tile[(4 * sq + 1) * CC + co];
        v.z = tile[(4 * sq + 2) * CC + co];
        v.w = tile[(4 * sq + 3) * CC + co];
        __builtin_nontemporal_store(
            v, (vfloat4*)(out_feat + (((size_t)(b * CC + c) * KK + k) * SS + 4 * sq)));
    }

    if (t < 24) {
        const int d   = t >> 3;
        const int sq2 = t & 7;
        const vfloat4 v = *(vfloat4*)&txyz[d][4 * sq2];
        __builtin_nontemporal_store(
            v, (vfloat4*)(out_xyz + (((size_t)(b * 3 + d) * KK + k) * SS + 4 * sq2)));
    }
}

extern "C" void kernel_launch(void* const* d_in, const int* in_sizes, int n_in,
                              void* d_out, int out_size, void* d_ws, size_t ws_size,
                              hipStream_t stream) {
    const float* xyz     = (const float*)d_in[0];   // [2][16384][3]
    const float* new_xyz = (const float*)d_in[1];   // [2][4096][3]
    const float* feat    = (const float*)d_in[2];   // [2][128][16384]
    float* out = (float*)d_out;

    // Workspace layout (17.5 MB total):
    int*   idx_buf = (int*)d_ws;                                  // 1 MB
    float* xyzw    = (float*)((char*)d_ws + (1 << 20));           // 512 KB
    float* feat_t  = (float*)((char*)d_ws + (1 << 20) + (512 << 10)); // 16 MB

    transpose_prep_kernel<<<dim3(BB * (NN / 64)), dim3(256), 0, stream>>>(
        feat, xyz, feat_t, xyzw);

    ball_query_kernel<<<dim3(BB * KK / 4), dim3(256), 0, stream>>>(
        xyzw, new_xyz, idx_buf);

    group_kernel<<<dim3(BB * KK), dim3(256), 0, stream>>>(
        xyzw, new_xyz, feat_t, idx_buf, out);
}